// Round 1
// baseline (265.182 us; speedup 1.0000x reference)
//
#include <hip/hip_runtime.h>

// x: (B=8, L=8192, D=512) fp32.  out: (B, 2048, D) fp32.
// out[b,i,d] = (sum_{l<=4(i+1)-1} x[b,l,d]) / (4(i+1))
//
// Fused single-pass chunked scan (R6): replaces the two-kernel structure.
// Each thread streams its 64-row chunk ONCE, keeps its 16 local-cumsum
// checkpoints in REGISTERS (16 x vf4 = 64 VGPR), publishes its chunk total,
// crosses a manual grid barrier (all 512 blocks co-resident: 2 blocks/CU,
// 8 waves/CU, no LDS -> dispatch is guaranteed greedy), then adds the
// exclusive prefix of chunk totals and writes the FINAL scaled output once.
//
// Eliminated vs R5 structure: 32 MiB checkpoint write + 32 MiB re-read +
// 32 MiB rewrite + second kernel launch. Remaining traffic = 128 MiB x-read
// + 32 MiB out-write + 2 MiB sums (~162 MiB ~ 27 us roofline).
//
// Cross-XCD correctness (Guideline 16): __syncthreads drains every wave's
// stores to its L2 (vmcnt(0) before s_barrier); thread0's __threadfence()
// at agent scope emits buffer_wbl2 sc1 (L2 writeback) before the release
// atomicAdd; spinners use agent-scope atomic loads; the post-spin
// __threadfence() acquires (buffer_inv) so the plain prefix-loop loads
// re-fetch fresh sums lines (which then L2-cache normally).

#define BB   8
#define LL   8192
#define DD4  128            // D / 4 (float4 granularity)
#define NC   128            // chunks along L
#define CL   (LL / NC)      // 64 rows per chunk
#define OPC  (CL / 4)       // 16 outputs per chunk per column
#define OL   (LL / 4)       // 2048 output rows
#define NBLK 512            // grid size; must all be co-resident
#define SUMS_BYTES ((size_t)BB * NC * DD4 * 16)   // 2 MiB of chunk totals

typedef float vf4 __attribute__((ext_vector_type(4)));

__global__ __launch_bounds__(256) void ds_fused(const vf4* __restrict__ x,
                                                vf4* __restrict__ sums,
                                                unsigned int* __restrict__ cnt,
                                                vf4* __restrict__ out) {
    const int tid = blockIdx.x * blockDim.x + threadIdx.x;
    const int d4 = tid & (DD4 - 1);
    const int c  = (tid >> 7) & (NC - 1);
    const int b  = tid >> 14;

    const vf4* p = x + (((size_t)b * LL + c * CL) * DD4 + d4);

    // ---- phase A: stream chunk, checkpoints -> registers ----
    vf4 v[OPC];                       // fully statically indexed (stays in VGPRs)
    vf4 s = (vf4)0.f;
    #pragma unroll
    for (int j = 0; j < CL; j += 8) {
        // 8 independent NT loads in flight before any use (x never re-read)
        vf4 v0 = __builtin_nontemporal_load(&p[(j + 0) * DD4]);
        vf4 v1 = __builtin_nontemporal_load(&p[(j + 1) * DD4]);
        vf4 v2 = __builtin_nontemporal_load(&p[(j + 2) * DD4]);
        vf4 v3 = __builtin_nontemporal_load(&p[(j + 3) * DD4]);
        vf4 v4 = __builtin_nontemporal_load(&p[(j + 4) * DD4]);
        vf4 v5 = __builtin_nontemporal_load(&p[(j + 5) * DD4]);
        vf4 v6 = __builtin_nontemporal_load(&p[(j + 6) * DD4]);
        vf4 v7 = __builtin_nontemporal_load(&p[(j + 7) * DD4]);
        s += v0 + v1 + v2 + v3;
        v[(j >> 2) + 0] = s;
        s += v4 + v5 + v6 + v7;
        v[(j >> 2) + 1] = s;
    }
    sums[(b * NC + c) * DD4 + d4] = s;      // chunk total (cached store)

    // ---- manual grid barrier ----
    __syncthreads();                        // all waves: vmcnt(0) -> stores in L2
    if (threadIdx.x == 0) {
        __threadfence();                    // agent release: wbl2 -> L3/HBM
        __hip_atomic_fetch_add(cnt, 1u, __ATOMIC_RELEASE, __HIP_MEMORY_SCOPE_AGENT);
        while (__hip_atomic_load(cnt, __ATOMIC_RELAXED, __HIP_MEMORY_SCOPE_AGENT) < NBLK)
            __builtin_amdgcn_s_sleep(8);    // ~512-cycle poll backoff
        __threadfence();                    // agent acquire: invalidate L1/L2
    }
    __syncthreads();

    // ---- phase B: exclusive prefix over preceding chunk totals ----
    // 4 independent accumulators for ILP; sums is 2 MiB, L2-resident after
    // first touch (post-invalidate loads are plain/cacheable).
    vf4 r0 = (vf4)0.f, r1 = (vf4)0.f, r2 = (vf4)0.f, r3 = (vf4)0.f;
    const vf4* sp = sums + b * NC * DD4 + d4;
    int q = 0;
    for (; q + 4 <= c; q += 4) {
        r0 += sp[(q + 0) * DD4];
        r1 += sp[(q + 1) * DD4];
        r2 += sp[(q + 2) * DD4];
        r3 += sp[(q + 3) * DD4];
    }
    for (; q < c; ++q) r0 += sp[q * DD4];
    const vf4 r = (r0 + r1) + (r2 + r3);

    // ---- phase C: scale registers, single final write ----
    vf4* o = out + (((size_t)b * OL + c * OPC) * DD4 + d4);
    const int base = c * CL;
    #pragma unroll
    for (int k = 0; k < OPC; ++k) {
        const float inv = 1.0f / (float)(base + 4 * k + 4);
        __builtin_nontemporal_store((v[k] + r) * inv, &o[(size_t)k * DD4]);
    }
}

extern "C" void kernel_launch(void* const* d_in, const int* in_sizes, int n_in,
                              void* d_out, int out_size, void* d_ws, size_t ws_size,
                              hipStream_t stream) {
    const vf4* x = (const vf4*)d_in[0];
    vf4* out = (vf4*)d_out;
    vf4* sums = (vf4*)d_ws;                 // 2 MiB, fully written each launch
    unsigned int* cnt = (unsigned int*)((char*)d_ws + SUMS_BYTES);

    // barrier counter must start at 0 (ws is poisoned between iterations);
    // hipMemsetAsync is graph-capturable (memset node).
    hipMemsetAsync(cnt, 0, 64, stream);
    ds_fused<<<NBLK, 256, 0, stream>>>(x, sums, cnt, out);
}